// Round 3
// baseline (40.077 us; speedup 1.0000x reference)
//
#include <hip/hip_runtime.h>
#include <stdint.h>

// Problem constants (from setup_inputs): x (4096, 2048) int32 {0,1},
// references (1024, 2048) float32 {0,1}, out (4096, 1024) float32.
constexpr int B_ROWS  = 4096;
constexpr int D_ROWS  = 1024;
constexpr int L_LEN   = 2048;
constexpr int L_WORDS = L_LEN / 64;   // 32 packed uint64 per row

// ---------------------------------------------------------------------------
// Kernel 1: bit-pack both inputs.
// Each wave handles one 256-element group: lane reads 4 consecutive elements
// (int4/float4, 16B/lane coalesced), 4 x __ballot produce 4 uint64 words.
// Bit i of word (g,k) = element g*256 + i*4 + k. The same within-row
// permutation is applied to x and refs, so popcount(xw ^ rw) summed over a
// row is exactly the Hamming distance (permutation-invariant).
// ---------------------------------------------------------------------------
__global__ __launch_bounds__(256) void pack_bits_kernel(
    const int* __restrict__ x, const float* __restrict__ r,
    uint64_t* __restrict__ xp, uint64_t* __restrict__ rp,
    int groups_x, int groups_total)
{
  const int lane   = threadIdx.x & 63;
  const int wave   = (int)((blockIdx.x * blockDim.x + threadIdx.x) >> 6);
  const int nwaves = (int)((gridDim.x * blockDim.x) >> 6);

  for (int g = wave; g < groups_total; g += nwaves) {   // g is wave-uniform
    if (g < groups_x) {
      const int4 v = *reinterpret_cast<const int4*>(x + (size_t)g * 256 + lane * 4);
      uint64_t m0 = __ballot(v.x != 0);
      uint64_t m1 = __ballot(v.y != 0);
      uint64_t m2 = __ballot(v.z != 0);
      uint64_t m3 = __ballot(v.w != 0);
      if (lane == 0) {
        uint64_t* p = xp + (size_t)g * 4;
        p[0] = m0; p[1] = m1; p[2] = m2; p[3] = m3;
      }
    } else {
      const int gr = g - groups_x;
      const float4 v = *reinterpret_cast<const float4*>(r + (size_t)gr * 256 + lane * 4);
      uint64_t m0 = __ballot(v.x != 0.0f);
      uint64_t m1 = __ballot(v.y != 0.0f);
      uint64_t m2 = __ballot(v.z != 0.0f);
      uint64_t m3 = __ballot(v.w != 0.0f);
      if (lane == 0) {
        uint64_t* p = rp + (size_t)gr * 4;
        p[0] = m0; p[1] = m1; p[2] = m2; p[3] = m3;
      }
    }
  }
}

// ---------------------------------------------------------------------------
// Kernel 2: popcount "GEMM". Block computes a 64 (b) x 128 (d) output tile.
// 256 threads = 16 tr x 16 tc; thread tile TB=4 b-rows x TD=8 d-cols.
// LDS holds both packed tiles word-major ([w][row], padded) so the K-loop
// reads are bank-conflict-free:
//   x  reads: rows tr*4+i contiguous (32B) -> ds_read_b128, banks 8*tr apart
//   r  reads: rows tc+16j, lanes tc=0..15 -> 16 distinct even banks
// Staging writes land 2-way (rs) / 4-way (xs) -- cheap, one-shot.
// ---------------------------------------------------------------------------
constexpr int BM = 64;
constexpr int BN = 128;
constexpr int XPAD = BM + 2;   // 66: row stride 528B = multiple of 16B (b128)
constexpr int RPAD = BN + 1;   // 129: row stride 1032B -> 2-way staging, free

__global__ __launch_bounds__(256) void hamming_kernel(
    const uint64_t* __restrict__ xp, const uint64_t* __restrict__ rp,
    float* __restrict__ out)
{
  __shared__ __align__(16) uint64_t xs[L_WORDS][XPAD];
  __shared__ __align__(16) uint64_t rs[L_WORDS][RPAD];

  const int t   = threadIdx.x;
  const int bm0 = blockIdx.x * BM;
  const int bn0 = blockIdx.y * BN;

  // Stage packed x tile: 64 rows x 32 words. Consecutive t -> consecutive w
  // (coalesced 8B global reads; two rows per wave, contiguous 512B).
  for (int i = t; i < BM * L_WORDS; i += 256) {
    const int row = i / L_WORDS, w = i % L_WORDS;
    xs[w][row] = xp[(size_t)(bm0 + row) * L_WORDS + w];
  }
  // Stage packed ref tile: 128 rows x 32 words.
  for (int i = t; i < BN * L_WORDS; i += 256) {
    const int row = i / L_WORDS, w = i % L_WORDS;
    rs[w][row] = rp[(size_t)(bn0 + row) * L_WORDS + w];
  }
  __syncthreads();

  const int tc = t & 15;    // d-col group
  const int tr = t >> 4;    // b-row group

  uint32_t acc[4][8];
#pragma unroll
  for (int i = 0; i < 4; ++i)
#pragma unroll
    for (int j = 0; j < 8; ++j) acc[i][j] = 0u;

#pragma unroll 4
  for (int w = 0; w < L_WORDS; ++w) {
    uint64_t xv[4], rv[8];
#pragma unroll
    for (int i = 0; i < 4; ++i) xv[i] = xs[w][tr * 4 + i];
#pragma unroll
    for (int j = 0; j < 8; ++j) rv[j] = rs[w][tc + 16 * j];
#pragma unroll
    for (int i = 0; i < 4; ++i)
#pragma unroll
      for (int j = 0; j < 8; ++j)
        acc[i][j] = (uint32_t)__popcll(xv[i] ^ rv[j]) + acc[i][j];
  }

  // out = (hamming - L/2) / (0.5*sqrt(L)); exact-integer hamming.
  const float inv_std = 0.04419417382415922f;  // 1 / (0.5*sqrt(2048))
#pragma unroll
  for (int i = 0; i < 4; ++i) {
    const int b = bm0 + tr * 4 + i;
#pragma unroll
    for (int j = 0; j < 8; ++j) {
      const int d = bn0 + tc + 16 * j;
      out[(size_t)b * D_ROWS + d] = ((float)acc[i][j] - 1024.0f) * inv_std;
    }
  }
}

extern "C" void kernel_launch(void* const* d_in, const int* in_sizes, int n_in,
                              void* d_out, int out_size, void* d_ws, size_t ws_size,
                              hipStream_t stream) {
  const int*   x = (const int*)d_in[0];     // (4096, 2048) int32
  const float* r = (const float*)d_in[1];   // (1024, 2048) float32
  float*     out = (float*)d_out;           // (4096, 1024) float32

  uint64_t* xp = (uint64_t*)d_ws;                               // 1 MiB
  uint64_t* rp = xp + (size_t)B_ROWS * L_WORDS;                 // +256 KiB

  const int groups_x = B_ROWS * L_LEN / 256;                    // 32768
  const int groups_r = D_ROWS * L_LEN / 256;                    // 8192
  const int groups_total = groups_x + groups_r;                 // 40960

  pack_bits_kernel<<<2048, 256, 0, stream>>>(x, r, xp, rp, groups_x, groups_total);

  dim3 grid(B_ROWS / BM, D_ROWS / BN);  // (64, 8) = 512 blocks
  hamming_kernel<<<grid, 256, 0, stream>>>(xp, rp, out);
}

// Round 4
// 39.434 us; speedup vs baseline: 1.0163x; 1.0163x over previous
//
#include <hip/hip_runtime.h>
#include <stdint.h>

// Problem constants: x (4096, 2048) int32 {0,1}, references (1024, 2048)
// float32 {0,1}, out (4096, 1024) float32.
constexpr int B_ROWS  = 4096;
constexpr int D_ROWS  = 1024;
constexpr int L_LEN   = 2048;
constexpr int L_WORDS = L_LEN / 64;   // 32 packed uint64 per row

// ---------------------------------------------------------------------------
// Kernel 1 (UNCHANGED from R2 — control for timing attribution):
// bit-pack both inputs via wave64 __ballot. Bit i of word (g,k) = element
// g*256 + i*4 + k; same permutation for x and refs, so popcount(xor) is the
// exact Hamming distance.
// ---------------------------------------------------------------------------
__global__ __launch_bounds__(256) void pack_bits_kernel(
    const int* __restrict__ x, const float* __restrict__ r,
    uint64_t* __restrict__ xp, uint64_t* __restrict__ rp,
    int groups_x, int groups_total)
{
  const int lane   = threadIdx.x & 63;
  const int wave   = (int)((blockIdx.x * blockDim.x + threadIdx.x) >> 6);
  const int nwaves = (int)((gridDim.x * blockDim.x) >> 6);

  for (int g = wave; g < groups_total; g += nwaves) {
    if (g < groups_x) {
      const int4 v = *reinterpret_cast<const int4*>(x + (size_t)g * 256 + lane * 4);
      uint64_t m0 = __ballot(v.x != 0);
      uint64_t m1 = __ballot(v.y != 0);
      uint64_t m2 = __ballot(v.z != 0);
      uint64_t m3 = __ballot(v.w != 0);
      if (lane == 0) {
        uint64_t* p = xp + (size_t)g * 4;
        p[0] = m0; p[1] = m1; p[2] = m2; p[3] = m3;
      }
    } else {
      const int gr = g - groups_x;
      const float4 v = *reinterpret_cast<const float4*>(r + (size_t)gr * 256 + lane * 4);
      uint64_t m0 = __ballot(v.x != 0.0f);
      uint64_t m1 = __ballot(v.y != 0.0f);
      uint64_t m2 = __ballot(v.z != 0.0f);
      uint64_t m3 = __ballot(v.w != 0.0f);
      if (lane == 0) {
        uint64_t* p = rp + (size_t)gr * 4;
        p[0] = m0; p[1] = m1; p[2] = m2; p[3] = m3;
      }
    }
  }
}

// ---------------------------------------------------------------------------
// Kernel 2: popcount GEMM, 64(b) x 128(d) tile, 256 threads (16tc x 16tr),
// thread tile TB=4 x TD=8.
// LDS row-major [row][WPAD=34]: row stride 272 B = 17*16 B (b128-aligned).
// Compute reads are ds_read_b128 (2 words at once):
//   xv banks: (16*tr + 4*i + 4*w2)%32 -> tr,tr+2 collide = 2-way (free, m136)
//   rv banks: (4*tc + 4*w2)%32       -> tc,tc+8 collide  = 2-way (free)
// Staging: b64, row=t>>5 w=t&31 -> bank 4*row+2*w covers all banks at the
// 4-bank-cycle b64 floor (conflict-free). Global reads 8B coalesced.
// K-loop: explicit register ping-pong (load pair s+1 while computing s) so
// LDS latency is hidden even at 2 waves/SIMD.
// ---------------------------------------------------------------------------
constexpr int BM   = 64;
constexpr int BN   = 128;
constexpr int WPAD = 34;   // 32 words + 2 pad -> 272B row stride

__global__ __launch_bounds__(256, 2) void hamming_kernel(
    const uint64_t* __restrict__ xp, const uint64_t* __restrict__ rp,
    float* __restrict__ out)
{
  __shared__ __align__(16) uint64_t xs[BM][WPAD];  // 17408 B
  __shared__ __align__(16) uint64_t rs[BN][WPAD];  // 34816 B  (52224 total)

  const int t   = threadIdx.x;
  const int bm0 = blockIdx.x * BM;
  const int bn0 = blockIdx.y * BN;

  // Stage x tile: 64 rows x 32 words, one b64 per thread per step.
  for (int i = t; i < BM * L_WORDS; i += 256) {
    const int row = i >> 5, w = i & 31;
    xs[row][w] = xp[(size_t)(bm0 + row) * L_WORDS + w];
  }
  // Stage ref tile: 128 rows x 32 words.
  for (int i = t; i < BN * L_WORDS; i += 256) {
    const int row = i >> 5, w = i & 31;
    rs[row][w] = rp[(size_t)(bn0 + row) * L_WORDS + w];
  }
  __syncthreads();

  const int tc = t & 15;   // d-col group
  const int tr = t >> 4;   // b-row group

  uint32_t acc[4][8] = {};

  // Register ping-pong buffers: one 2-word step each.
  uint64_t xA[4][2], rA[8][2], xB[4][2], rB[8][2];

#define LOADX(dst, w2) do {                                                   \
    _Pragma("unroll") for (int _i = 0; _i < 4; ++_i) {                        \
      ulonglong2 _v = *reinterpret_cast<const ulonglong2*>(                   \
          &xs[tr * 4 + _i][(w2) * 2]);                                        \
      dst[_i][0] = _v.x; dst[_i][1] = _v.y;                                   \
    } } while (0)

#define LOADR(dst, w2) do {                                                   \
    _Pragma("unroll") for (int _j = 0; _j < 8; ++_j) {                        \
      ulonglong2 _v = *reinterpret_cast<const ulonglong2*>(                   \
          &rs[tc + 16 * _j][(w2) * 2]);                                       \
      dst[_j][0] = _v.x; dst[_j][1] = _v.y;                                   \
    } } while (0)

#define COMP(xr, rr) do {                                                     \
    _Pragma("unroll") for (int _i = 0; _i < 4; ++_i)                          \
      _Pragma("unroll") for (int _j = 0; _j < 8; ++_j) {                      \
        acc[_i][_j] += (uint32_t)__popcll(xr[_i][0] ^ rr[_j][0]);             \
        acc[_i][_j] += (uint32_t)__popcll(xr[_i][1] ^ rr[_j][1]);             \
      } } while (0)

  LOADX(xA, 0); LOADR(rA, 0);
#pragma unroll 2
  for (int s = 0; s < 7; ++s) {
    LOADX(xB, 2 * s + 1); LOADR(rB, 2 * s + 1);
    COMP(xA, rA);
    LOADX(xA, 2 * s + 2); LOADR(rA, 2 * s + 2);
    COMP(xB, rB);
  }
  LOADX(xB, 15); LOADR(rB, 15);
  COMP(xA, rA);
  COMP(xB, rB);

#undef LOADX
#undef LOADR
#undef COMP

  // out = (hamming - L/2) / (0.5*sqrt(L)); exact-integer hamming.
  const float inv_std = 0.04419417382415922f;  // 1 / (0.5*sqrt(2048))
#pragma unroll
  for (int i = 0; i < 4; ++i) {
    const int b = bm0 + tr * 4 + i;
#pragma unroll
    for (int j = 0; j < 8; ++j) {
      const int d = bn0 + tc + 16 * j;
      out[(size_t)b * D_ROWS + d] = ((float)acc[i][j] - 1024.0f) * inv_std;
    }
  }
}

extern "C" void kernel_launch(void* const* d_in, const int* in_sizes, int n_in,
                              void* d_out, int out_size, void* d_ws, size_t ws_size,
                              hipStream_t stream) {
  const int*   x = (const int*)d_in[0];     // (4096, 2048) int32
  const float* r = (const float*)d_in[1];   // (1024, 2048) float32
  float*     out = (float*)d_out;           // (4096, 1024) float32

  uint64_t* xp = (uint64_t*)d_ws;                               // 1 MiB
  uint64_t* rp = xp + (size_t)B_ROWS * L_WORDS;                 // +256 KiB

  const int groups_x = B_ROWS * L_LEN / 256;                    // 32768
  const int groups_r = D_ROWS * L_LEN / 256;                    // 8192
  const int groups_total = groups_x + groups_r;                 // 40960

  pack_bits_kernel<<<2048, 256, 0, stream>>>(x, r, xp, rp, groups_x, groups_total);

  dim3 grid(B_ROWS / BM, D_ROWS / BN);  // (64, 8) = 512 blocks
  hamming_kernel<<<grid, 256, 0, stream>>>(xp, rp, out);
}